// Round 1
// baseline (116.682 us; speedup 1.0000x reference)
//
#include <hip/hip_runtime.h>
#include <hip/hip_bf16.h>
#include <stdint.h>

#define QMAX 127.0f

typedef __attribute__((ext_vector_type(8))) short bf16x8;
typedef __attribute__((ext_vector_type(4))) float f32x4;
typedef __attribute__((ext_vector_type(4))) short s16x4;

typedef __attribute__((address_space(1))) const void GVoid;
typedef __attribute__((address_space(3))) void LVoid;

__device__ inline short quant1(float x, float scale) {
    float q = rintf(x / scale);              // IEEE div + RNE == jnp.round(x/scale)
    q = fminf(fmaxf(q, -QMAX), QMAX);
    __hip_bfloat16 h = __float2bfloat16(q);  // exact: |q| <= 127 integer
    union { __hip_bfloat16 h; short s; } u;
    u.h = h;
    return u.s;
}

// ---- kernel 1: quantize rhs along axis 0 (per column f), store B^T bf16 [F][K] ----
__global__ void quant_rhs_kernel(const float* __restrict__ rhs,
                                 short* __restrict__ Bt,
                                 float* __restrict__ rscale) {
    const int f = blockIdx.x;      // column 0..511
    const int t = threadIdx.x;     // 0..63
    float v[8];
    float amax = 0.f;
#pragma unroll
    for (int i = 0; i < 8; ++i) {
        v[i] = rhs[(size_t)(t + 64 * i) * 512 + f];
        amax = fmaxf(amax, fabsf(v[i]));
    }
#pragma unroll
    for (int m = 1; m <= 32; m <<= 1)
        amax = fmaxf(amax, __shfl_xor(amax, m, 64));
    const float scale = amax > 0.f ? amax / QMAX : 1.0f;
    if (t == 0) rscale[f] = scale;
#pragma unroll
    for (int i = 0; i < 8; ++i)
        Bt[(size_t)f * 512 + t + 64 * i] = quant1(v[i], scale);
}

// ---- kernel 2: quantize lhs along axis 2 (per row), one wave per row ----
__global__ void quant_lhs_kernel(const float* __restrict__ lhs,
                                 short* __restrict__ Aq,
                                 float* __restrict__ lscale) {
    const int lane = threadIdx.x & 63;
    const int wave = threadIdx.x >> 6;
    const int row = blockIdx.x * 4 + wave;
    const float* rp = lhs + (size_t)row * 512;
    const float4 a = *(const float4*)(rp + lane * 4);
    const float4 b = *(const float4*)(rp + 256 + lane * 4);
    float amax = fmaxf(fmaxf(fmaxf(fabsf(a.x), fabsf(a.y)), fmaxf(fabsf(a.z), fabsf(a.w))),
                       fmaxf(fmaxf(fabsf(b.x), fabsf(b.y)), fmaxf(fabsf(b.z), fabsf(b.w))));
#pragma unroll
    for (int m = 1; m <= 32; m <<= 1)
        amax = fmaxf(amax, __shfl_xor(amax, m, 64));
    const float scale = amax > 0.f ? amax / QMAX : 1.0f;
    if (lane == 0) lscale[row] = scale;
    s16x4 o0, o1;
    o0.x = quant1(a.x, scale); o0.y = quant1(a.y, scale);
    o0.z = quant1(a.z, scale); o0.w = quant1(a.w, scale);
    o1.x = quant1(b.x, scale); o1.y = quant1(b.y, scale);
    o1.z = quant1(b.z, scale); o1.w = quant1(b.w, scale);
    short* op = Aq + (size_t)row * 512;
    *(s16x4*)(op + lane * 4) = o0;
    *(s16x4*)(op + 256 + lane * 4) = o1;
}

// ---- kernel 3: bf16 MFMA GEMM [65536x512] x [512x512]^T with scale epilogue ----
// m97 structure: 128x128 tile, BK=64, 4 waves (2x2), 4x4 frags of 16x16x32,
// global_load_lds width=16, linear LDS, 2-barrier loop.
__global__ __launch_bounds__(256) void gemm_kernel(const short* __restrict__ Aq,
                                                   const short* __restrict__ Bt,
                                                   const float* __restrict__ lscale,
                                                   const float* __restrict__ rscale,
                                                   float* __restrict__ out) {
    __shared__ char lds[32768];  // A tile [128][64]bf16 @0, B^T tile [128][64]bf16 @16384

    const int tid  = threadIdx.x;
    const int lane = tid & 63;
    const int wave = tid >> 6;
    const int wr   = wave >> 1;   // wave row 0..1
    const int wc   = wave & 1;    // wave col 0..1
    const int bid  = blockIdx.x;
    const int m0   = (bid >> 2) * 128;   // 512 m-tiles
    const int n0   = (bid & 3) * 128;    // 4 n-tiles

    f32x4 acc[4][4];
#pragma unroll
    for (int i = 0; i < 4; ++i)
#pragma unroll
        for (int j = 0; j < 4; ++j)
            acc[i][j] = (f32x4){0.f, 0.f, 0.f, 0.f};

    for (int kt = 0; kt < 512; kt += 64) {
        __syncthreads();   // previous tile fully consumed before overwrite
        // stage A and B^T tiles: 16KB each, 8 global_load_lds_dwordx4 per thread
#pragma unroll
        for (int c = 0; c < 4; ++c) {
            const int chunk = (c * 4 + wave) * 1024;     // wave-uniform 1KB chunk
            const int d     = chunk + lane * 16;         // this lane's dest byte
            const int row   = d >> 7;                    // tile row (A) / col (B)
            const int kb    = (d & 127) >> 1;            // k element offset
            const short* srcA = Aq + (size_t)(m0 + row) * 512 + kt + kb;
            __builtin_amdgcn_global_load_lds((GVoid*)srcA, (LVoid*)(lds + chunk), 16, 0, 0);
            const short* srcB = Bt + (size_t)(n0 + row) * 512 + kt + kb;
            __builtin_amdgcn_global_load_lds((GVoid*)srcB, (LVoid*)(lds + 16384 + chunk), 16, 0, 0);
        }
        __syncthreads();   // staging complete (barrier drains vmcnt)

#pragma unroll
        for (int kk = 0; kk < 2; ++kk) {
            const int kbyte = kk * 64 + ((lane >> 4) * 16);  // k = kk*32 + (lane>>4)*8
            bf16x8 af[4], bf[4];
#pragma unroll
            for (int mi = 0; mi < 4; ++mi) {
                const int row = wr * 64 + mi * 16 + (lane & 15);
                af[mi] = *(const bf16x8*)(lds + row * 128 + kbyte);
            }
#pragma unroll
            for (int ni = 0; ni < 4; ++ni) {
                const int col = wc * 64 + ni * 16 + (lane & 15);
                bf[ni] = *(const bf16x8*)(lds + 16384 + col * 128 + kbyte);
            }
#pragma unroll
            for (int mi = 0; mi < 4; ++mi)
#pragma unroll
                for (int ni = 0; ni < 4; ++ni)
                    acc[mi][ni] = __builtin_amdgcn_mfma_f32_16x16x32_bf16(
                        af[mi], bf[ni], acc[mi][ni], 0, 0, 0);
        }
    }

    // epilogue: C/D layout col=lane&15, row=(lane>>4)*4+reg  [m89-verified]
    const int rgroup = (lane >> 4) * 4;
#pragma unroll
    for (int mi = 0; mi < 4; ++mi) {
#pragma unroll
        for (int ni = 0; ni < 4; ++ni) {
            const int col = n0 + wc * 64 + ni * 16 + (lane & 15);
            const float rs = rscale[col];
#pragma unroll
            for (int r = 0; r < 4; ++r) {
                const int row = m0 + wr * 64 + mi * 16 + rgroup + r;
                out[(size_t)row * 512 + col] = acc[mi][ni][r] * lscale[row] * rs;
            }
        }
    }
}

extern "C" void kernel_launch(void* const* d_in, const int* in_sizes, int n_in,
                              void* d_out, int out_size, void* d_ws, size_t ws_size,
                              hipStream_t stream) {
    const float* lhs = (const float*)d_in[0];   // [4,16384,512] f32
    const float* rhs = (const float*)d_in[1];   // [512,512] f32
    float* out = (float*)d_out;                 // [4,16384,512] f32

    // ws layout: Bt bf16 [512][512] (512KB) | rscale f32[512] | lscale f32[65536] | Aq bf16 [65536][512] (64MB)
    char* ws = (char*)d_ws;
    short* Bt     = (short*)ws;
    float* rscale = (float*)(ws + 524288);
    float* lscale = (float*)(ws + 524288 + 4096);
    short* Aq     = (short*)(ws + 1048576);

    const int rows = in_sizes[0] / 512;         // 65536

    quant_rhs_kernel<<<512, 64, 0, stream>>>(rhs, Bt, rscale);
    quant_lhs_kernel<<<rows / 4, 256, 0, stream>>>(lhs, Aq, lscale);
    gemm_kernel<<<(rows / 128) * 4, 256, 0, stream>>>(Aq, Bt, lscale, rscale, out);
}

// Round 2
// 101.892 us; speedup vs baseline: 1.1452x; 1.1452x over previous
//
#include <hip/hip_runtime.h>
#include <hip/hip_bf16.h>
#include <stdint.h>

#define QMAX 127.0f

typedef __attribute__((ext_vector_type(8))) short bf16x8;
typedef __attribute__((ext_vector_type(4))) float f32x4;
typedef __attribute__((ext_vector_type(4))) short s16x4;

__device__ inline short quant1(float x, float scale) {
    float q = rintf(x / scale);              // IEEE div + RNE == jnp.round(x/scale)
    q = fminf(fmaxf(q, -QMAX), QMAX);
    __hip_bfloat16 h = __float2bfloat16(q);  // exact: |q| <= 127 integer
    union { __hip_bfloat16 h; short s; } u;
    u.h = h;
    return u.s;
}

// ---- kernel 1: quantize rhs along axis 0 (per column f), store B^T bf16 [F][K] ----
__global__ void quant_rhs_kernel(const float* __restrict__ rhs,
                                 short* __restrict__ Bt,
                                 float* __restrict__ rscale) {
    const int f = blockIdx.x;      // column 0..511
    const int t = threadIdx.x;     // 0..63
    float v[8];
    float amax = 0.f;
#pragma unroll
    for (int i = 0; i < 8; ++i) {
        v[i] = rhs[(size_t)(t + 64 * i) * 512 + f];
        amax = fmaxf(amax, fabsf(v[i]));
    }
#pragma unroll
    for (int m = 1; m <= 32; m <<= 1)
        amax = fmaxf(amax, __shfl_xor(amax, m, 64));
    const float scale = amax > 0.f ? amax / QMAX : 1.0f;
    if (t == 0) rscale[f] = scale;
#pragma unroll
    for (int i = 0; i < 8; ++i)
        Bt[(size_t)f * 512 + t + 64 * i] = quant1(v[i], scale);
}

// ---- kernel 2: fused quant(lhs) + GEMM, one block = 64 rows x full N=512 ----
// Phase 1: quantize 64 lhs rows to bf16 into XOR-swizzled LDS (register ds_write
//          path, so swizzle is legal -- rule #21 both-sides-or-neither).
// Phase 2: barrier-free GEMM: A frags from swizzled LDS (2-way conflicts = free),
//          B frags straight from L2-resident Bt [512][512] bf16 (wave reads whole
//          64B lines), 16x16x32 bf16 MFMA, scale epilogue.
__global__ __launch_bounds__(512, 4) void fused_kernel(const float* __restrict__ lhs,
                                                       const short* __restrict__ Bt,
                                                       const float* __restrict__ rscale,
                                                       float* __restrict__ out) {
    __shared__ short A[32768];   // [64 rows][512 k] bf16, swizzled
    __shared__ float lsc[64];

    const int tid  = threadIdx.x;
    const int lane = tid & 63;
    const int wave = tid >> 6;         // 0..7
    const int m0   = blockIdx.x << 6;  // 64 rows per block

    // ---- phase 1: quantize rows m0..m0+63 into LDS ----
#pragma unroll
    for (int rr = 0; rr < 8; ++rr) {
        const int row = rr * 8 + wave;          // 8 waves read 8 consecutive rows
        const float* rp = lhs + (size_t)(m0 + row) * 512;
        const float4 a = *(const float4*)(rp + lane * 4);
        const float4 b = *(const float4*)(rp + 256 + lane * 4);
        float amax = fmaxf(fmaxf(fmaxf(fabsf(a.x), fabsf(a.y)), fmaxf(fabsf(a.z), fabsf(a.w))),
                           fmaxf(fmaxf(fabsf(b.x), fabsf(b.y)), fmaxf(fabsf(b.z), fabsf(b.w))));
#pragma unroll
        for (int m = 1; m <= 32; m <<= 1)
            amax = fmaxf(amax, __shfl_xor(amax, m, 64));
        const float scale = amax > 0.f ? amax / QMAX : 1.0f;
        if (lane == 0) lsc[row] = scale;
        s16x4 o0, o1;
        o0.x = quant1(a.x, scale); o0.y = quant1(a.y, scale);
        o0.z = quant1(a.z, scale); o0.w = quant1(a.w, scale);
        o1.x = quant1(b.x, scale); o1.y = quant1(b.y, scale);
        o1.z = quant1(b.z, scale); o1.w = quant1(b.w, scale);
        char* Ab = (char*)A + row * 1024;
        const int sw = (row & 7) << 4;                    // XOR bits 4..6
        *(s16x4*)(Ab + ((lane * 8) ^ sw))       = o0;     // bytes [0,512)
        *(s16x4*)(Ab + ((512 + lane * 8) ^ sw)) = o1;     // bytes [512,1024)
    }
    __syncthreads();

    // ---- phase 2: GEMM 64x512, wave w owns cols [w*64, w*64+64) ----
    const int lane15  = lane & 15;
    const int laneHi  = lane >> 4;
    const int colBase = wave * 64;

    f32x4 acc[4][4];
#pragma unroll
    for (int i = 0; i < 4; ++i)
#pragma unroll
        for (int j = 0; j < 4; ++j)
            acc[i][j] = (f32x4){0.f, 0.f, 0.f, 0.f};

#pragma unroll
    for (int ks = 0; ks < 16; ++ks) {            // k = ks*32
        const int kbyte = ks * 64 + laneHi * 16; // byte offset of this lane's 8 k-elems
        bf16x8 af[4], bfr[4];
#pragma unroll
        for (int mi = 0; mi < 4; ++mi) {
            const int row = mi * 16 + lane15;
            af[mi] = *(const bf16x8*)((const char*)A + row * 1024 + (kbyte ^ ((row & 7) << 4)));
        }
#pragma unroll
        for (int ni = 0; ni < 4; ++ni) {
            const int col = colBase + ni * 16 + lane15;
            bfr[ni] = *(const bf16x8*)(Bt + (size_t)col * 512 + ks * 32 + laneHi * 8);
        }
#pragma unroll
        for (int mi = 0; mi < 4; ++mi)
#pragma unroll
            for (int ni = 0; ni < 4; ++ni)
                acc[mi][ni] = __builtin_amdgcn_mfma_f32_16x16x32_bf16(
                    af[mi], bfr[ni], acc[mi][ni], 0, 0, 0);
    }

    // ---- epilogue: C/D layout col=lane&15, row=(lane>>4)*4+reg ----
    float rs[4];
#pragma unroll
    for (int ni = 0; ni < 4; ++ni)
        rs[ni] = rscale[colBase + ni * 16 + lane15];
    const int rg = laneHi * 4;
#pragma unroll
    for (int mi = 0; mi < 4; ++mi) {
#pragma unroll
        for (int r = 0; r < 4; ++r) {
            const int lrow = mi * 16 + rg + r;
            const float ls = lsc[lrow];
            float* op = out + (size_t)(m0 + lrow) * 512;
#pragma unroll
            for (int ni = 0; ni < 4; ++ni)
                op[colBase + ni * 16 + lane15] = acc[mi][ni][r] * ls * rs[ni];
        }
    }
}

extern "C" void kernel_launch(void* const* d_in, const int* in_sizes, int n_in,
                              void* d_out, int out_size, void* d_ws, size_t ws_size,
                              hipStream_t stream) {
    const float* lhs = (const float*)d_in[0];   // [4,16384,512] f32
    const float* rhs = (const float*)d_in[1];   // [512,512] f32
    float* out = (float*)d_out;                 // [4,16384,512] f32

    // ws layout: Bt bf16 [512][512] (512KB) | rscale f32[512]
    char* ws = (char*)d_ws;
    short* Bt     = (short*)ws;
    float* rscale = (float*)(ws + 524288);

    const int rows = in_sizes[0] / 512;         // 65536

    quant_rhs_kernel<<<512, 64, 0, stream>>>(rhs, Bt, rscale);
    fused_kernel<<<rows / 64, 512, 0, stream>>>(lhs, Bt, rscale, out);
}